// Round 13
// baseline (4010.374 us; speedup 1.0000x reference)
//
#include <hip/hip_runtime.h>
#include <stdint.h>

#define TSEQ 512
#define NB   64
#define EMB  300
#define HID  300
#define G4   1200
#define KKP  150     // k-pairs (300/2)
#define NT   9
#define MTOT (TSEQ*NB)   // 32768

// MFMA lstm geometry: 2 dirs x 4 batch-groups(16) x 10 hid-blocks(32 rows)
#define NP 10
#define NQ 4
#define NWG (2*NQ*NP)    // 80 workgroups, 512 threads each
#define KSTEPS 10        // K padded to 320
#define HROWS 160        // h2g/Ae rows (k-pairs), rows 150..159 stay zero

typedef _Float16 f16x8 __attribute__((ext_vector_type(8)));
typedef float f32x4 __attribute__((ext_vector_type(4)));
union H2U { uint32_t u; _Float16 h[2]; };

__device__ __forceinline__ uint32_t packf2(float a, float b) {
  H2U u; u.h[0] = (_Float16)a; u.h[1] = (_Float16)b; return u.u;
}
__device__ __forceinline__ float fexp(float x) {
  return __builtin_amdgcn_exp2f(x * 1.44269504088896f);
}
__device__ __forceinline__ float sigm(float x) {
  return __builtin_amdgcn_rcpf(1.0f + fexp(-x));
}
__device__ __forceinline__ float ftanh(float x) {
  return 1.0f - 2.0f * __builtin_amdgcn_rcpf(fexp(2.0f * x) + 1.0f);
}

__global__ __launch_bounds__(256) void prep_bias(
    const float* __restrict__ bihf, const float* __restrict__ bhhf,
    const float* __restrict__ bihb, const float* __restrict__ bhhb,
    float* __restrict__ bias) {
  int i = blockIdx.x * 256 + threadIdx.x;
  if (i < G4) {
    bias[i]       = bihf[i] + bhhf[i];
    bias[G4 + i]  = bihb[i] + bhhb[i];
  }
}

// ---- W_ih AND W_hh -> per-lane MFMA A-frags, gates stacked in M ----
// blk = ((((kind*2+d)*NP + p)*8 + w)*KSTEPS + ks ; kind 0 = W_ih, 1 = W_hh.
// A row m=(gamma=m>>2, rr=m&3); hid = 32p + 4w + rr; k = ks*32 + (l>>4)*8 + e.
__global__ __launch_bounds__(64) void prep_wf(
    const float* __restrict__ Wihf, const float* __restrict__ Wihb,
    const float* __restrict__ Whhf, const float* __restrict__ Whhb,
    uint32_t* __restrict__ wf) {
  int blk = blockIdx.x;
  int ks = blk % KSTEPS; int tmp = blk / KSTEPS;
  int w = tmp & 7; tmp >>= 3;
  int p = tmp % NP; tmp /= NP;
  int d = tmp & 1; int kind = tmp >> 1;
  int lane = threadIdx.x;
  const float* W = kind ? (d ? Whhb : Whhf) : (d ? Wihb : Wihf);
  int m = lane & 15;
  int gamma = m >> 2, rr = m & 3;
  int hid = 32 * p + 4 * w + rr;
  int k0 = ks * 32 + (lane >> 4) * 8;
  float vals[8];
  #pragma unroll
  for (int e = 0; e < 8; ++e) {
    int k = k0 + e;
    vals[e] = (hid < 300 && k < 300) ? W[(size_t)(gamma * 300 + hid) * 300 + k] : 0.0f;
  }
  uint4 dw;
  dw.x = packf2(vals[0], vals[1]);
  dw.y = packf2(vals[2], vals[3]);
  dw.z = packf2(vals[4], vals[5]);
  dw.w = packf2(vals[6], vals[7]);
  *(uint4*)(wf + ((size_t)blk * 64 + lane) * 4) = dw;
}

// ---- zero per-WG flags + h2 double buffer (every launch: graph replay) ----
__global__ __launch_bounds__(256) void init_sync(
    uint32_t* __restrict__ flags, uint32_t* __restrict__ h2g) {
  int i = blockIdx.x * 256 + threadIdx.x;
  if (i < 8 * 16) flags[i] = 0;
  if (i < 2 * 2 * HROWS * 64) h2g[i] = 0;
}

// ---- gather embeddings -> packed f16x2, layout Ae[kk][m] (m = t*64+b) ----
// rows 150..159 zero-padded (MFMA B side must be 0, never garbage/NaN)
__global__ __launch_bounds__(256) void gather_emb(
    const int* __restrict__ x, const float* __restrict__ emb,
    uint32_t* __restrict__ Ae) {
  __shared__ __align__(16) uint32_t buf[64 * KKP];
  __shared__ int idxs[64];
  int tid = threadIdx.x;
  int m0 = blockIdx.x * 64;
  if (tid < 64) {
    int mm = m0 + tid;
    idxs[tid] = x[(size_t)(mm & 63) * TSEQ + (mm >> 6)];
  }
  __syncthreads();
  for (int i = tid; i < 64 * KKP; i += 256) {
    int mm = i / KKP, kk = i % KKP;
    float2 v = *(const float2*)(emb + (size_t)idxs[mm] * EMB + 2 * kk);
    buf[i] = packf2(v.x, v.y);
  }
  __syncthreads();
  for (int i = tid; i < 64 * KKP; i += 256) {
    int kk = i >> 6, mm = i & 63;
    Ae[(size_t)kk * MTOT + m0 + mm] = buf[mm * KKP + kk];
  }
  for (int i = tid; i < 64 * (HROWS - KKP); i += 256) {
    int kk = KKP + (i >> 6), mm = i & 63;
    Ae[(size_t)kk * MTOT + m0 + mm] = 0u;
  }
}

// ---- fused MFMA LSTM: 512-thread WGs, fan-in 10, per-WG flag ----
// __launch_bounds__(512,1): 2 waves/SIMD -> 256-VGPR cap (r12's (512,2)
// capped at 128 and spilled the weight fragments -> 2.5x regression).
__global__ __launch_bounds__(512, 1) void lstm_mfma(
    const uint32_t* __restrict__ wf, const uint32_t* __restrict__ Ae,
    const float* __restrict__ bias,
    uint32_t* __restrict__ h2g, uint32_t* __restrict__ hs16,
    uint32_t* __restrict__ flags) {
  const int wg = blockIdx.x;           // ((d*NQ+q)*NP + p)
  const int p  = wg % NP;
  const int dq = wg / NP;
  const int q  = dq & 3;
  const int d  = dq >> 2;
  const int tid = threadIdx.x;
  const int w = tid >> 6;              // 0..7
  const int lane = tid & 63;
  const int G = lane >> 4;             // 0..3
  const int b = lane & 15;
  const int hidbase = 32 * p + 4 * w;
  const bool valid = hidbase < 300;    // p=9, w>=3 waves are padding
  const int bglob = 16 * q + b;

  __shared__ float xch[8 * 256];       // per-wave 4x4 gate transpose buffer

  // A fragments in registers: W_ih (ai) + W_hh (ah), 10 x uint4 each
  uint4 ai[KSTEPS], ah[KSTEPS];
  const int blkI = (((0 * 2 + d) * NP + p) * 8 + w) * KSTEPS;
  const int blkH = (((1 * 2 + d) * NP + p) * 8 + w) * KSTEPS;
  #pragma unroll
  for (int ks = 0; ks < KSTEPS; ++ks) {
    ai[ks] = *(const uint4*)(wf + ((size_t)(blkI + ks) * 64 + lane) * 4);
    ah[ks] = *(const uint4*)(wf + ((size_t)(blkH + ks) * 64 + lane) * 4);
  }

  // per-lane bias for chain0 accumulator init (gate G, rows hidbase..+3)
  float b4[4] = {0.f, 0.f, 0.f, 0.f};
  if (valid) {
    #pragma unroll
    for (int j = 0; j < 4; ++j)
      b4[j] = bias[d * G4 + G * 300 + hidbase + j];
  }

  uint32_t* flagbase = flags + dq * 16;
  uint32_t* myflag = flagbase + p;
  float cstate = 0.0f;

  for (int s = 0; s < TSEQ; ++s) {
    const int t = d ? (TSEQ - 1 - s) : s;

    // issue Ae B-fragment loads FIRST: independent of h, L3 latency hides
    // under the flag poll below
    uint32_t ab[KSTEPS][4];
    {
      const uint32_t* asrc = Ae + (size_t)t * NB + bglob;
      #pragma unroll
      for (int ks = 0; ks < KSTEPS; ++ks)
        #pragma unroll
        for (int j = 0; j < 4; ++j)
          ab[ks][j] = asrc[(size_t)(ks * 16 + G * 4 + j) * MTOT];
    }

    // poll the group's 10 per-WG flags (relaxed, MALL-direct; 1 cacheline)
    if (s > 0) {
      const uint32_t sv = (uint32_t)s;
      for (;;) {
        uint32_t v0 = sv;
        if (lane < NP)
          v0 = __hip_atomic_load(flagbase + lane, __ATOMIC_RELAXED,
                                 __HIP_MEMORY_SCOPE_AGENT);
        if (__all((int)(v0 >= sv))) break;
      }
      asm volatile("" ::: "memory");   // compile-time fence: keep h loads below
    }

    // h B-fragments straight from MALL (relaxed agent): 40 dwords
    const uint32_t* hb = h2g + (size_t)(((s + 1) & 1) * 2 + d) * (HROWS * 64)
                         + bglob;
    uint32_t bf[KSTEPS][4];
    #pragma unroll
    for (int ks = 0; ks < KSTEPS; ++ks)
      #pragma unroll
      for (int j = 0; j < 4; ++j)
        bf[ks][j] = __hip_atomic_load(hb + (size_t)(ks * 16 + G * 4 + j) * 64,
                                      __ATOMIC_RELAXED, __HIP_MEMORY_SCOPE_AGENT);

    // two independent MFMA chains: input-projection + recurrence
    f32x4 acc0, acc1;
    acc0[0] = b4[0]; acc0[1] = b4[1]; acc0[2] = b4[2]; acc0[3] = b4[3];
    acc1[0] = 0.f; acc1[1] = 0.f; acc1[2] = 0.f; acc1[3] = 0.f;
    #pragma unroll
    for (int ks = 0; ks < KSTEPS; ++ks) {
      union { uint4 u; f16x8 v; } aiu, ahu;
      union { uint32_t u[4]; f16x8 v; } abu, bfu;
      aiu.u = ai[ks]; ahu.u = ah[ks];
      abu.u[0] = ab[ks][0]; abu.u[1] = ab[ks][1];
      abu.u[2] = ab[ks][2]; abu.u[3] = ab[ks][3];
      bfu.u[0] = bf[ks][0]; bfu.u[1] = bf[ks][1];
      bfu.u[2] = bf[ks][2]; bfu.u[3] = bf[ks][3];
      acc0 = __builtin_amdgcn_mfma_f32_16x16x32_f16(aiu.v, abu.v, acc0, 0, 0, 0);
      acc1 = __builtin_amdgcn_mfma_f32_16x16x32_f16(ahu.v, bfu.v, acc1, 0, 0, 0);
    }

    // in-wave 4x4 transpose (rr x gate) via LDS, wave-synchronous
    #pragma unroll
    for (int j = 0; j < 4; ++j)
      xch[w * 256 + (j * 4 + G) * 16 + b] = acc0[j] + acc1[j];
    asm volatile("s_waitcnt lgkmcnt(0)" ::: "memory");
    __builtin_amdgcn_sched_barrier(0);
    float gi = xch[w * 256 + (G * 4 + 0) * 16 + b];
    float gf = xch[w * 256 + (G * 4 + 1) * 16 + b];
    float gg = xch[w * 256 + (G * 4 + 2) * 16 + b];
    float go = xch[w * 256 + (G * 4 + 3) * 16 + b];

    // cell update for row hidbase+G, batch bglob (c stays in register)
    float iv = sigm(gi), fv = sigm(gf), gv = ftanh(gg), ov = sigm(go);
    cstate = fv * cstate + iv * gv;
    float h = ov * ftanh(cstate);

    // pack pairs (rows even/odd) and publish h to MALL
    float hp = __shfl_xor(h, 16);      // G0<->G1, G2<->G3
    uint32_t dw = packf2(h, hp);
    int kk = (hidbase + G) >> 1;       // = 16p + 2w + (G>>1), <= 149 when valid
    if (valid && (G & 1) == 0) {
      uint32_t* dst = h2g + (size_t)((s & 1) * 2 + d) * (HROWS * 64)
                      + (size_t)kk * 64 + bglob;
      __hip_atomic_store(dst, dw, __ATOMIC_RELAXED, __HIP_MEMORY_SCOPE_AGENT);
    }
    // barrier's vmcnt(0) drain certifies ALL 8 waves' h stores are at MALL
    __syncthreads();
    if (tid == 0)
      __hip_atomic_store(myflag, (uint32_t)(s + 1), __ATOMIC_RELAXED,
                         __HIP_MEMORY_SCOPE_AGENT);
    // archive store AFTER the flag: off the critical path, drains by next step
    if (valid && (G & 1) == 0)
      hs16[((size_t)d * MTOT + (size_t)t * NB + bglob) * 152 + kk] = dw;
  }
}

// ---- logits from f16 h pairs; 16 tb per WG; softmax -> probs ----
__global__ __launch_bounds__(256) void logits_probs(
    const uint32_t* __restrict__ hs16, const float* __restrict__ Wlin,
    const float* __restrict__ blin, float* __restrict__ probs) {
  __shared__ float Ws[NT * 600];
  __shared__ float bs[NT];
  int tid = threadIdx.x;
  for (int i = tid; i < NT * 600; i += 256) Ws[i] = Wlin[i];
  if (tid < NT) bs[tid] = blin[tid];
  __syncthreads();
  int wave = tid >> 6, lane = tid & 63;
  for (int it = 0; it < 4; ++it) {
    int tb = blockIdx.x * 16 + wave * 4 + it;
    const uint32_t* hf = hs16 + (size_t)tb * 152;
    const uint32_t* hb = hs16 + ((size_t)MTOT + tb) * 152;
    uint32_t fa[3], ga[3];
    fa[0] = hf[lane]; fa[1] = hf[64 + lane];
    fa[2] = (lane < 22) ? hf[128 + lane] : 0u;
    ga[0] = hb[lane]; ga[1] = hb[64 + lane];
    ga[2] = (lane < 22) ? hb[128 + lane] : 0u;
    float p[NT];
    #pragma unroll
    for (int k = 0; k < NT; ++k) p[k] = 0.f;
    #pragma unroll
    for (int c = 0; c < 3; ++c) {
      int kk = c * 64 + lane;
      if (kk < KKP) {
        H2U uf; uf.u = fa[c];
        H2U ug; ug.u = ga[c];
        float hf0 = (float)uf.h[0], hf1 = (float)uf.h[1];
        float hb0 = (float)ug.h[0], hb1 = (float)ug.h[1];
        #pragma unroll
        for (int k = 0; k < NT; ++k)
          p[k] += hf0 * Ws[k * 600 + 2 * kk] + hf1 * Ws[k * 600 + 2 * kk + 1]
                + hb0 * Ws[k * 600 + 300 + 2 * kk] + hb1 * Ws[k * 600 + 300 + 2 * kk + 1];
      }
    }
    #pragma unroll
    for (int off = 32; off > 0; off >>= 1)
      #pragma unroll
      for (int k = 0; k < NT; ++k) p[k] += __shfl_xor(p[k], off);
    float l[NT]; float mx = -1e30f;
    #pragma unroll
    for (int k = 0; k < NT; ++k) { l[k] = p[k] + bs[k]; mx = fmaxf(mx, l[k]); }
    float ssum = 0.f;
    #pragma unroll
    for (int k = 0; k < NT; ++k) ssum += expf(l[k] - mx);
    int t = tb >> 6, bb = tb & 63;
    if (lane < NT)
      probs[((size_t)bb * TSEQ + t) * NT + lane] = expf(l[lane] - mx) / ssum;
  }
}

// ---- CRF numerator per batch ----
__global__ __launch_bounds__(256) void crf_num(
    const int* __restrict__ y, const float* __restrict__ probs,
    const float* __restrict__ strt, const float* __restrict__ endt,
    const float* __restrict__ trans, float* __restrict__ nums) {
  int b = blockIdx.x, tid = threadIdx.x;
  __shared__ float r1[256], r2[256];
  float s = 0.f, cnt = 0.f;
  for (int t = tid; t < TSEQ; t += 256) {
    int yc = y[(size_t)b * TSEQ + t];
    cnt += (yc != -1) ? 1.f : 0.f;
    if (t >= 1) {
      int yp = y[(size_t)b * TSEQ + t - 1];
      float mask = (yc != -1) ? 1.f : 0.f;
      s += mask * (trans[yp * NT + yc] + probs[((size_t)b * TSEQ + t) * NT + yc]);
    }
  }
  r1[tid] = s; r2[tid] = cnt;
  __syncthreads();
  for (int off = 128; off > 0; off >>= 1) {
    if (tid < off) { r1[tid] += r1[tid + off]; r2[tid] += r2[tid + off]; }
    __syncthreads();
  }
  if (tid == 0) {
    int y0 = y[(size_t)b * TSEQ];
    int seqlen = (int)(r2[0] + 0.5f);
    int ylast = y[(size_t)b * TSEQ + seqlen - 1];
    nums[b] = strt[y0] + probs[((size_t)b * TSEQ) * NT + y0] + r1[0] + endt[ylast];
  }
}

// ---- CRF forward algorithm: one wave per batch ----
__global__ __launch_bounds__(64) void crf_alpha(
    const int* __restrict__ y, const float* __restrict__ probs,
    const float* __restrict__ strt, const float* __restrict__ endt,
    const float* __restrict__ trans, float* __restrict__ dens) {
  int b = blockIdx.x, lane = threadIdx.x;
  __shared__ float P[TSEQ * NT];
  __shared__ float msk[TSEQ];
  for (int i = lane; i < TSEQ * NT; i += 64) P[i] = probs[(size_t)b * TSEQ * NT + i];
  for (int i = lane; i < TSEQ; i += 64) msk[i] = (y[(size_t)b * TSEQ + i] != -1) ? 1.f : 0.f;
  asm volatile("s_waitcnt lgkmcnt(0) vmcnt(0)" ::: "memory");
  int li = lane < NT ? lane : NT - 1;
  float trc[NT];
  #pragma unroll
  for (int j = 0; j < NT; ++j) trc[j] = trans[j * NT + li];
  float al = strt[li] + P[li];
  for (int t = 1; t < TSEQ; ++t) {
    float e = P[t * NT + li];
    float m = msk[t];
    float tmp[NT]; float mx = -1e30f;
    #pragma unroll
    for (int j = 0; j < NT; ++j) {
      float aj = __shfl(al, j);
      tmp[j] = aj + trc[j];
      mx = fmaxf(mx, tmp[j]);
    }
    float sum = 0.f;
    #pragma unroll
    for (int j = 0; j < NT; ++j) sum += expf(tmp[j] - mx);
    float nxt = e + mx + logf(sum);
    al = (m > 0.5f) ? nxt : al;
  }
  float vv = al + endt[li];
  float mx = -1e30f;
  #pragma unroll
  for (int j = 0; j < NT; ++j) mx = fmaxf(mx, __shfl(vv, j));
  float sum = 0.f;
  #pragma unroll
  for (int j = 0; j < NT; ++j) sum += expf(__shfl(vv, j) - mx);
  if (lane == 0) dens[b] = mx + logf(sum);
}

__global__ __launch_bounds__(64) void final_sum(
    const float* __restrict__ nums, const float* __restrict__ dens,
    float* __restrict__ out) {
  __shared__ float r[64];
  int tid = threadIdx.x;
  r[tid] = nums[tid] - dens[tid];
  __syncthreads();
  for (int off = 32; off > 0; off >>= 1) {
    if (tid < off) r[tid] += r[tid + off];
    __syncthreads();
  }
  if (tid == 0) out[(size_t)MTOT * NT] = -r[0];
}

extern "C" void kernel_launch(void* const* d_in, const int* in_sizes, int n_in,
                              void* d_out, int out_size, void* d_ws, size_t ws_size,
                              hipStream_t stream) {
  (void)in_sizes; (void)n_in; (void)out_size;
  const int*   x     = (const int*)d_in[0];
  const int*   y     = (const int*)d_in[1];
  const float* emb   = (const float*)d_in[2];
  const float* Wihf  = (const float*)d_in[3];
  const float* Whhf  = (const float*)d_in[4];
  const float* bihf  = (const float*)d_in[5];
  const float* bhhf  = (const float*)d_in[6];
  const float* Wihb  = (const float*)d_in[7];
  const float* Whhb  = (const float*)d_in[8];
  const float* bihb  = (const float*)d_in[9];
  const float* bhhb  = (const float*)d_in[10];
  const float* Wlin  = (const float*)d_in[11];
  const float* blin  = (const float*)d_in[12];
  const float* strt  = (const float*)d_in[13];
  const float* endt  = (const float*)d_in[14];
  const float* trans = (const float*)d_in[15];
  float* outp = (float*)d_out;

  char* ws = (char*)d_ws;
  const size_t OFF_WF    = 0;            // 3200 blocks * 1024 B = 3,276,800
  const size_t OFF_BIAS  = 3276800;      // 9,600
  const size_t OFF_NUMS  = 3286400;      // 256
  const size_t OFF_DENS  = 3286656;      // 256
  const size_t OFF_FLAGS = 3286912;      // 4,096
  const size_t OFF_H2G   = 3291008;      // 2*2*160*64*4 = 163,840
  const size_t OFF_AE    = 3454848;      // 160*32768*4 = 20,971,520
  const size_t OFF_HS16  = 24426368;     // 2*32768*152*4 = 39,845,888 -> 64,272,256
  if (ws_size < 64272256ull) return;

  uint32_t* wf    = (uint32_t*)(ws + OFF_WF);
  float*    bias  = (float*)(ws + OFF_BIAS);
  float*    nums  = (float*)(ws + OFF_NUMS);
  float*    dens  = (float*)(ws + OFF_DENS);
  uint32_t* flags = (uint32_t*)(ws + OFF_FLAGS);
  uint32_t* h2g   = (uint32_t*)(ws + OFF_H2G);
  uint32_t* Ae    = (uint32_t*)(ws + OFF_AE);
  uint32_t* hs16  = (uint32_t*)(ws + OFF_HS16);

  prep_wf<<<dim3(2 * 2 * NP * 8 * KSTEPS), 64, 0, stream>>>(Wihf, Wihb, Whhf, Whhb, wf);
  prep_bias<<<dim3((G4 + 255) / 256), 256, 0, stream>>>(bihf, bhhf, bihb, bhhb, bias);
  init_sync<<<dim3(160), 256, 0, stream>>>(flags, h2g);
  gather_emb<<<dim3(MTOT / 64), 256, 0, stream>>>(x, emb, Ae);
  lstm_mfma<<<dim3(NWG), 512, 0, stream>>>(wf, Ae, bias, h2g, hs16, flags);
  logits_probs<<<dim3(MTOT / 16), 256, 0, stream>>>(hs16, Wlin, blin, outp);
  crf_num<<<dim3(NB), 256, 0, stream>>>(y, outp, strt, endt, trans, nums);
  crf_alpha<<<dim3(NB), 64, 0, stream>>>(y, outp, strt, endt, trans, dens);
  final_sum<<<1, 64, 0, stream>>>(nums, dens, outp);
}

// Round 14
// 1943.223 us; speedup vs baseline: 2.0638x; 2.0638x over previous
//
#include <hip/hip_runtime.h>
#include <stdint.h>

#define TSEQ 512
#define NB   64
#define EMB  300
#define HID  300
#define G4   1200
#define KKP  150     // k-pairs (300/2)
#define NT   9
#define MTOT (TSEQ*NB)   // 32768

// MFMA lstm geometry: 2 dirs x 4 batch-groups(16) x 10 hid-blocks(32 rows)
// 256-thread WGs (the only config that gets >128 VGPRs); wave owns 2 subtiles.
#define NP 10
#define NQ 4
#define NWG (2*NQ*NP)    // 80 workgroups, 256 threads each
#define KSTEPS 10        // K padded to 320
#define HROWS 160        // h2g/Ae rows (k-pairs), rows 150..159 stay zero

typedef _Float16 f16x8 __attribute__((ext_vector_type(8)));
typedef float f32x4 __attribute__((ext_vector_type(4)));
union H2U { uint32_t u; _Float16 h[2]; };

__device__ __forceinline__ uint32_t packf2(float a, float b) {
  H2U u; u.h[0] = (_Float16)a; u.h[1] = (_Float16)b; return u.u;
}
__device__ __forceinline__ float fexp(float x) {
  return __builtin_amdgcn_exp2f(x * 1.44269504088896f);
}
__device__ __forceinline__ float sigm(float x) {
  return __builtin_amdgcn_rcpf(1.0f + fexp(-x));
}
__device__ __forceinline__ float ftanh(float x) {
  return 1.0f - 2.0f * __builtin_amdgcn_rcpf(fexp(2.0f * x) + 1.0f);
}

__global__ __launch_bounds__(256) void prep_bias(
    const float* __restrict__ bihf, const float* __restrict__ bhhf,
    const float* __restrict__ bihb, const float* __restrict__ bhhb,
    float* __restrict__ bias) {
  int i = blockIdx.x * 256 + threadIdx.x;
  if (i < G4) {
    bias[i]       = bihf[i] + bhhf[i];
    bias[G4 + i]  = bihb[i] + bhhb[i];
  }
}

// ---- W_ih AND W_hh -> per-lane MFMA A-frags, gates stacked in M ----
// blk = ((((kind*2+d)*NP + p)*8 + tt)*KSTEPS + ks ; kind 0 = W_ih, 1 = W_hh.
// A row m=(gamma=m>>2, rr=m&3); hid = 32p + 4*tt + rr; k = ks*32 + (l>>4)*8 + e.
__global__ __launch_bounds__(64) void prep_wf(
    const float* __restrict__ Wihf, const float* __restrict__ Wihb,
    const float* __restrict__ Whhf, const float* __restrict__ Whhb,
    uint32_t* __restrict__ wf) {
  int blk = blockIdx.x;
  int ks = blk % KSTEPS; int tmp = blk / KSTEPS;
  int tt = tmp & 7; tmp >>= 3;
  int p = tmp % NP; tmp /= NP;
  int d = tmp & 1; int kind = tmp >> 1;
  int lane = threadIdx.x;
  const float* W = kind ? (d ? Whhb : Whhf) : (d ? Wihb : Wihf);
  int m = lane & 15;
  int gamma = m >> 2, rr = m & 3;
  int hid = 32 * p + 4 * tt + rr;
  int k0 = ks * 32 + (lane >> 4) * 8;
  float vals[8];
  #pragma unroll
  for (int e = 0; e < 8; ++e) {
    int k = k0 + e;
    vals[e] = (hid < 300 && k < 300) ? W[(size_t)(gamma * 300 + hid) * 300 + k] : 0.0f;
  }
  uint4 dw;
  dw.x = packf2(vals[0], vals[1]);
  dw.y = packf2(vals[2], vals[3]);
  dw.z = packf2(vals[4], vals[5]);
  dw.w = packf2(vals[6], vals[7]);
  *(uint4*)(wf + ((size_t)blk * 64 + lane) * 4) = dw;
}

// ---- zero per-WG flags + h2 double buffer (every launch: graph replay) ----
__global__ __launch_bounds__(256) void init_sync(
    uint32_t* __restrict__ flags, uint32_t* __restrict__ h2g) {
  int i = blockIdx.x * 256 + threadIdx.x;
  if (i < 8 * 16) flags[i] = 0;
  if (i < 2 * 2 * HROWS * 64) h2g[i] = 0;
}

// ---- gather embeddings -> packed f16x2, layout Ae[kk][m] (m = t*64+b) ----
// rows 150..159 zero-padded (MFMA B side must be 0, never garbage/NaN)
__global__ __launch_bounds__(256) void gather_emb(
    const int* __restrict__ x, const float* __restrict__ emb,
    uint32_t* __restrict__ Ae) {
  __shared__ __align__(16) uint32_t buf[64 * KKP];
  __shared__ int idxs[64];
  int tid = threadIdx.x;
  int m0 = blockIdx.x * 64;
  if (tid < 64) {
    int mm = m0 + tid;
    idxs[tid] = x[(size_t)(mm & 63) * TSEQ + (mm >> 6)];
  }
  __syncthreads();
  for (int i = tid; i < 64 * KKP; i += 256) {
    int mm = i / KKP, kk = i % KKP;
    float2 v = *(const float2*)(emb + (size_t)idxs[mm] * EMB + 2 * kk);
    buf[i] = packf2(v.x, v.y);
  }
  __syncthreads();
  for (int i = tid; i < 64 * KKP; i += 256) {
    int kk = i >> 6, mm = i & 63;
    Ae[(size_t)kk * MTOT + m0 + mm] = buf[mm * KKP + kk];
  }
  for (int i = tid; i < 64 * (HROWS - KKP); i += 256) {
    int kk = KKP + (i >> 6), mm = i & 63;
    Ae[(size_t)kk * MTOT + m0 + mm] = 0u;
  }
}

// ---- fused MFMA LSTM: 256-thread WGs, fan-in 10, 2 M-tiles per wave ----
// WG = (d,q,p); wave w owns subtiles tt=2w,2w+1 (rows 32p+8w .. +8) for all
// 4 gates. B-fragments (Ae, h) shared across both tiles. Per-WG single flag
// after __syncthreads (vmcnt drain); hs16 archive store after the flag.
__global__ __launch_bounds__(256, 1) void lstm_mfma(
    const uint32_t* __restrict__ wf, const uint32_t* __restrict__ Ae,
    const float* __restrict__ bias,
    uint32_t* __restrict__ h2g, uint32_t* __restrict__ hs16,
    uint32_t* __restrict__ flags) {
  const int wg = blockIdx.x;           // ((d*NQ+q)*NP + p)
  const int p  = wg % NP;
  const int dq = wg / NP;
  const int q  = dq & 3;
  const int d  = dq >> 2;
  const int tid = threadIdx.x;
  const int w = tid >> 6;              // 0..3
  const int lane = tid & 63;
  const int G = lane >> 4;             // 0..3
  const int b = lane & 15;
  const int bglob = 16 * q + b;

  __shared__ float xch[4][2][256];     // per-wave, per-tile 4x4 gate transpose

  // A fragments in registers: 2 tiles x (W_ih + W_hh) x 10 ksteps
  uint4 ai[2][KSTEPS], ah[2][KSTEPS];
  int hb0[2]; bool vld[2];
  #pragma unroll
  for (int i = 0; i < 2; ++i) {
    int tt = 2 * w + i;
    hb0[i] = 32 * p + 4 * tt;
    vld[i] = hb0[i] < 300;
    const int blkI = (((0 * 2 + d) * NP + p) * 8 + tt) * KSTEPS;
    const int blkH = (((1 * 2 + d) * NP + p) * 8 + tt) * KSTEPS;
    #pragma unroll
    for (int ks = 0; ks < KSTEPS; ++ks) {
      ai[i][ks] = *(const uint4*)(wf + ((size_t)(blkI + ks) * 64 + lane) * 4);
      ah[i][ks] = *(const uint4*)(wf + ((size_t)(blkH + ks) * 64 + lane) * 4);
    }
  }

  // per-lane bias for chain0 init (gate G, rows hb0[i]..+3)
  float b4[2][4];
  #pragma unroll
  for (int i = 0; i < 2; ++i)
    #pragma unroll
    for (int j = 0; j < 4; ++j)
      b4[i][j] = vld[i] ? bias[d * G4 + G * 300 + hb0[i] + j] : 0.0f;

  uint32_t* flagbase = flags + dq * 16;
  uint32_t* myflag = flagbase + p;
  float cst[2] = {0.f, 0.f};

  for (int s = 0; s < TSEQ; ++s) {
    const int t = d ? (TSEQ - 1 - s) : s;

    // Ae B-fragment loads FIRST (shared by both tiles): L3 latency hides
    // under the flag poll
    uint32_t ab[KSTEPS][4];
    {
      const uint32_t* asrc = Ae + (size_t)t * NB + bglob;
      #pragma unroll
      for (int ks = 0; ks < KSTEPS; ++ks)
        #pragma unroll
        for (int j = 0; j < 4; ++j)
          ab[ks][j] = asrc[(size_t)(ks * 16 + G * 4 + j) * MTOT];
    }

    // poll the group's 10 per-WG flags (1 cacheline, relaxed, MALL-direct)
    if (s > 0) {
      const uint32_t sv = (uint32_t)s;
      for (;;) {
        uint32_t v0 = sv;
        if (lane < NP)
          v0 = __hip_atomic_load(flagbase + lane, __ATOMIC_RELAXED,
                                 __HIP_MEMORY_SCOPE_AGENT);
        if (__all((int)(v0 >= sv))) break;
      }
      asm volatile("" ::: "memory");   // keep h loads below the poll
    }

    // h B-fragments straight from MALL (relaxed agent): 40 dwords, shared
    const uint32_t* hsrc = h2g + (size_t)(((s + 1) & 1) * 2 + d) * (HROWS * 64)
                           + bglob;
    uint32_t bf[KSTEPS][4];
    #pragma unroll
    for (int ks = 0; ks < KSTEPS; ++ks)
      #pragma unroll
      for (int j = 0; j < 4; ++j)
        bf[ks][j] = __hip_atomic_load(hsrc + (size_t)(ks * 16 + G * 4 + j) * 64,
                                      __ATOMIC_RELAXED, __HIP_MEMORY_SCOPE_AGENT);

    // 4 independent MFMA chains: (tile0,tile1) x (input-proj, recurrence)
    f32x4 a0c0, a0c1, a1c0, a1c1;
    a0c0[0] = b4[0][0]; a0c0[1] = b4[0][1]; a0c0[2] = b4[0][2]; a0c0[3] = b4[0][3];
    a1c0[0] = b4[1][0]; a1c0[1] = b4[1][1]; a1c0[2] = b4[1][2]; a1c0[3] = b4[1][3];
    a0c1[0] = 0.f; a0c1[1] = 0.f; a0c1[2] = 0.f; a0c1[3] = 0.f;
    a1c1[0] = 0.f; a1c1[1] = 0.f; a1c1[2] = 0.f; a1c1[3] = 0.f;
    #pragma unroll
    for (int ks = 0; ks < KSTEPS; ++ks) {
      union { uint32_t u[4]; f16x8 v; } abu, bfu;
      abu.u[0] = ab[ks][0]; abu.u[1] = ab[ks][1];
      abu.u[2] = ab[ks][2]; abu.u[3] = ab[ks][3];
      bfu.u[0] = bf[ks][0]; bfu.u[1] = bf[ks][1];
      bfu.u[2] = bf[ks][2]; bfu.u[3] = bf[ks][3];
      union { uint4 u; f16x8 v; } w0, w1, w2, w3;
      w0.u = ai[0][ks]; w1.u = ah[0][ks]; w2.u = ai[1][ks]; w3.u = ah[1][ks];
      a0c0 = __builtin_amdgcn_mfma_f32_16x16x32_f16(w0.v, abu.v, a0c0, 0, 0, 0);
      a0c1 = __builtin_amdgcn_mfma_f32_16x16x32_f16(w1.v, bfu.v, a0c1, 0, 0, 0);
      a1c0 = __builtin_amdgcn_mfma_f32_16x16x32_f16(w2.v, abu.v, a1c0, 0, 0, 0);
      a1c1 = __builtin_amdgcn_mfma_f32_16x16x32_f16(w3.v, bfu.v, a1c1, 0, 0, 0);
    }

    // in-wave 4x4 transposes (both tiles), one lgkm wait
    #pragma unroll
    for (int j = 0; j < 4; ++j) {
      xch[w][0][(j * 4 + G) * 16 + b] = a0c0[j] + a0c1[j];
      xch[w][1][(j * 4 + G) * 16 + b] = a1c0[j] + a1c1[j];
    }
    asm volatile("s_waitcnt lgkmcnt(0)" ::: "memory");
    __builtin_amdgcn_sched_barrier(0);

    // cell updates + h publish (to h2g only; hs16 deferred past the flag)
    uint32_t dwv[2]; int kkv[2];
    #pragma unroll
    for (int i = 0; i < 2; ++i) {
      float gi = xch[w][i][(G * 4 + 0) * 16 + b];
      float gf = xch[w][i][(G * 4 + 1) * 16 + b];
      float gg = xch[w][i][(G * 4 + 2) * 16 + b];
      float go = xch[w][i][(G * 4 + 3) * 16 + b];
      float iv = sigm(gi), fv = sigm(gf), gv = ftanh(gg), ov = sigm(go);
      float c = fv * cst[i] + iv * gv; cst[i] = c;
      float h = ov * ftanh(c);
      float hp = __shfl_xor(h, 16);    // rows G<->G^1
      dwv[i] = packf2(h, hp);
      kkv[i] = (hb0[i] + G) >> 1;      // = 16p + 2*tt + (G>>1)
      if (vld[i] && (G & 1) == 0) {
        uint32_t* dst = h2g + (size_t)((s & 1) * 2 + d) * (HROWS * 64)
                        + (size_t)kkv[i] * 64 + bglob;
        __hip_atomic_store(dst, dwv[i], __ATOMIC_RELAXED, __HIP_MEMORY_SCOPE_AGENT);
      }
    }
    // barrier's vmcnt(0) drain certifies all 4 waves' h stores are at MALL
    __syncthreads();
    if (tid == 0)
      __hip_atomic_store(myflag, (uint32_t)(s + 1), __ATOMIC_RELAXED,
                         __HIP_MEMORY_SCOPE_AGENT);
    // archive stores AFTER the flag: off the critical path
    #pragma unroll
    for (int i = 0; i < 2; ++i)
      if (vld[i] && (G & 1) == 0)
        hs16[((size_t)d * MTOT + (size_t)t * NB + bglob) * 152 + kkv[i]] = dwv[i];
  }
}

// ---- logits from f16 h pairs; 16 tb per WG; softmax -> probs ----
__global__ __launch_bounds__(256) void logits_probs(
    const uint32_t* __restrict__ hs16, const float* __restrict__ Wlin,
    const float* __restrict__ blin, float* __restrict__ probs) {
  __shared__ float Ws[NT * 600];
  __shared__ float bs[NT];
  int tid = threadIdx.x;
  for (int i = tid; i < NT * 600; i += 256) Ws[i] = Wlin[i];
  if (tid < NT) bs[tid] = blin[tid];
  __syncthreads();
  int wave = tid >> 6, lane = tid & 63;
  for (int it = 0; it < 4; ++it) {
    int tb = blockIdx.x * 16 + wave * 4 + it;
    const uint32_t* hf = hs16 + (size_t)tb * 152;
    const uint32_t* hb = hs16 + ((size_t)MTOT + tb) * 152;
    uint32_t fa[3], ga[3];
    fa[0] = hf[lane]; fa[1] = hf[64 + lane];
    fa[2] = (lane < 22) ? hf[128 + lane] : 0u;
    ga[0] = hb[lane]; ga[1] = hb[64 + lane];
    ga[2] = (lane < 22) ? hb[128 + lane] : 0u;
    float p[NT];
    #pragma unroll
    for (int k = 0; k < NT; ++k) p[k] = 0.f;
    #pragma unroll
    for (int c = 0; c < 3; ++c) {
      int kk = c * 64 + lane;
      if (kk < KKP) {
        H2U uf; uf.u = fa[c];
        H2U ug; ug.u = ga[c];
        float hf0 = (float)uf.h[0], hf1 = (float)uf.h[1];
        float hb0 = (float)ug.h[0], hb1 = (float)ug.h[1];
        #pragma unroll
        for (int k = 0; k < NT; ++k)
          p[k] += hf0 * Ws[k * 600 + 2 * kk] + hf1 * Ws[k * 600 + 2 * kk + 1]
                + hb0 * Ws[k * 600 + 300 + 2 * kk] + hb1 * Ws[k * 600 + 300 + 2 * kk + 1];
      }
    }
    #pragma unroll
    for (int off = 32; off > 0; off >>= 1)
      #pragma unroll
      for (int k = 0; k < NT; ++k) p[k] += __shfl_xor(p[k], off);
    float l[NT]; float mx = -1e30f;
    #pragma unroll
    for (int k = 0; k < NT; ++k) { l[k] = p[k] + bs[k]; mx = fmaxf(mx, l[k]); }
    float ssum = 0.f;
    #pragma unroll
    for (int k = 0; k < NT; ++k) ssum += expf(l[k] - mx);
    int t = tb >> 6, bb = tb & 63;
    if (lane < NT)
      probs[((size_t)bb * TSEQ + t) * NT + lane] = expf(l[lane] - mx) / ssum;
  }
}

// ---- CRF numerator per batch ----
__global__ __launch_bounds__(256) void crf_num(
    const int* __restrict__ y, const float* __restrict__ probs,
    const float* __restrict__ strt, const float* __restrict__ endt,
    const float* __restrict__ trans, float* __restrict__ nums) {
  int b = blockIdx.x, tid = threadIdx.x;
  __shared__ float r1[256], r2[256];
  float s = 0.f, cnt = 0.f;
  for (int t = tid; t < TSEQ; t += 256) {
    int yc = y[(size_t)b * TSEQ + t];
    cnt += (yc != -1) ? 1.f : 0.f;
    if (t >= 1) {
      int yp = y[(size_t)b * TSEQ + t - 1];
      float mask = (yc != -1) ? 1.f : 0.f;
      s += mask * (trans[yp * NT + yc] + probs[((size_t)b * TSEQ + t) * NT + yc]);
    }
  }
  r1[tid] = s; r2[tid] = cnt;
  __syncthreads();
  for (int off = 128; off > 0; off >>= 1) {
    if (tid < off) { r1[tid] += r1[tid + off]; r2[tid] += r2[tid + off]; }
    __syncthreads();
  }
  if (tid == 0) {
    int y0 = y[(size_t)b * TSEQ];
    int seqlen = (int)(r2[0] + 0.5f);
    int ylast = y[(size_t)b * TSEQ + seqlen - 1];
    nums[b] = strt[y0] + probs[((size_t)b * TSEQ) * NT + y0] + r1[0] + endt[ylast];
  }
}

// ---- CRF forward algorithm: one wave per batch ----
__global__ __launch_bounds__(64) void crf_alpha(
    const int* __restrict__ y, const float* __restrict__ probs,
    const float* __restrict__ strt, const float* __restrict__ endt,
    const float* __restrict__ trans, float* __restrict__ dens) {
  int b = blockIdx.x, lane = threadIdx.x;
  __shared__ float P[TSEQ * NT];
  __shared__ float msk[TSEQ];
  for (int i = lane; i < TSEQ * NT; i += 64) P[i] = probs[(size_t)b * TSEQ * NT + i];
  for (int i = lane; i < TSEQ; i += 64) msk[i] = (y[(size_t)b * TSEQ + i] != -1) ? 1.f : 0.f;
  asm volatile("s_waitcnt lgkmcnt(0) vmcnt(0)" ::: "memory");
  int li = lane < NT ? lane : NT - 1;
  float trc[NT];
  #pragma unroll
  for (int j = 0; j < NT; ++j) trc[j] = trans[j * NT + li];
  float al = strt[li] + P[li];
  for (int t = 1; t < TSEQ; ++t) {
    float e = P[t * NT + li];
    float m = msk[t];
    float tmp[NT]; float mx = -1e30f;
    #pragma unroll
    for (int j = 0; j < NT; ++j) {
      float aj = __shfl(al, j);
      tmp[j] = aj + trc[j];
      mx = fmaxf(mx, tmp[j]);
    }
    float sum = 0.f;
    #pragma unroll
    for (int j = 0; j < NT; ++j) sum += expf(tmp[j] - mx);
    float nxt = e + mx + logf(sum);
    al = (m > 0.5f) ? nxt : al;
  }
  float vv = al + endt[li];
  float mx = -1e30f;
  #pragma unroll
  for (int j = 0; j < NT; ++j) mx = fmaxf(mx, __shfl(vv, j));
  float sum = 0.f;
  #pragma unroll
  for (int j = 0; j < NT; ++j) sum += expf(__shfl(vv, j) - mx);
  if (lane == 0) dens[b] = mx + logf(sum);
}

__global__ __launch_bounds__(64) void final_sum(
    const float* __restrict__ nums, const float* __restrict__ dens,
    float* __restrict__ out) {
  __shared__ float r[64];
  int tid = threadIdx.x;
  r[tid] = nums[tid] - dens[tid];
  __syncthreads();
  for (int off = 32; off > 0; off >>= 1) {
    if (tid < off) r[tid] += r[tid + off];
    __syncthreads();
  }
  if (tid == 0) out[(size_t)MTOT * NT] = -r[0];
}

extern "C" void kernel_launch(void* const* d_in, const int* in_sizes, int n_in,
                              void* d_out, int out_size, void* d_ws, size_t ws_size,
                              hipStream_t stream) {
  (void)in_sizes; (void)n_in; (void)out_size;
  const int*   x     = (const int*)d_in[0];
  const int*   y     = (const int*)d_in[1];
  const float* emb   = (const float*)d_in[2];
  const float* Wihf  = (const float*)d_in[3];
  const float* Whhf  = (const float*)d_in[4];
  const float* bihf  = (const float*)d_in[5];
  const float* bhhf  = (const float*)d_in[6];
  const float* Wihb  = (const float*)d_in[7];
  const float* Whhb  = (const float*)d_in[8];
  const float* bihb  = (const float*)d_in[9];
  const float* bhhb  = (const float*)d_in[10];
  const float* Wlin  = (const float*)d_in[11];
  const float* blin  = (const float*)d_in[12];
  const float* strt  = (const float*)d_in[13];
  const float* endt  = (const float*)d_in[14];
  const float* trans = (const float*)d_in[15];
  float* outp = (float*)d_out;

  char* ws = (char*)d_ws;
  const size_t OFF_WF    = 0;            // 3200 blocks * 1024 B = 3,276,800
  const size_t OFF_BIAS  = 3276800;      // 9,600
  const size_t OFF_NUMS  = 3286400;      // 256
  const size_t OFF_DENS  = 3286656;      // 256
  const size_t OFF_FLAGS = 3286912;      // 4,096
  const size_t OFF_H2G   = 3291008;      // 2*2*160*64*4 = 163,840
  const size_t OFF_AE    = 3454848;      // 160*32768*4 = 20,971,520
  const size_t OFF_HS16  = 24426368;     // 2*32768*152*4 = 39,845,888 -> 64,272,256
  if (ws_size < 64272256ull) return;

  uint32_t* wf    = (uint32_t*)(ws + OFF_WF);
  float*    bias  = (float*)(ws + OFF_BIAS);
  float*    nums  = (float*)(ws + OFF_NUMS);
  float*    dens  = (float*)(ws + OFF_DENS);
  uint32_t* flags = (uint32_t*)(ws + OFF_FLAGS);
  uint32_t* h2g   = (uint32_t*)(ws + OFF_H2G);
  uint32_t* Ae    = (uint32_t*)(ws + OFF_AE);
  uint32_t* hs16  = (uint32_t*)(ws + OFF_HS16);

  prep_wf<<<dim3(2 * 2 * NP * 8 * KSTEPS), 64, 0, stream>>>(Wihf, Wihb, Whhf, Whhb, wf);
  prep_bias<<<dim3((G4 + 255) / 256), 256, 0, stream>>>(bihf, bhhf, bihb, bhhb, bias);
  init_sync<<<dim3(160), 256, 0, stream>>>(flags, h2g);
  gather_emb<<<dim3(MTOT / 64), 256, 0, stream>>>(x, emb, Ae);
  lstm_mfma<<<dim3(NWG), 256, 0, stream>>>(wf, Ae, bias, h2g, hs16, flags);
  logits_probs<<<dim3(MTOT / 16), 256, 0, stream>>>(hs16, Wlin, blin, outp);
  crf_num<<<dim3(NB), 256, 0, stream>>>(y, outp, strt, endt, trans, nums);
  crf_alpha<<<dim3(NB), 64, 0, stream>>>(y, outp, strt, endt, trans, dens);
  final_sum<<<1, 64, 0, stream>>>(nums, dens, outp);
}

// Round 15
// 1764.174 us; speedup vs baseline: 2.2732x; 1.1015x over previous
//
#include <hip/hip_runtime.h>
#include <stdint.h>

#define TSEQ 512
#define NB   64
#define EMB  300
#define HID  300
#define G4   1200
#define KKP  150     // k-pairs (300/2)
#define NT   9
#define MTOT (TSEQ*NB)   // 32768

// MFMA lstm geometry: 2 dirs x 4 batch-groups(16) x 19 hid-blocks(16 rows)
#define NP 19
#define NQ 4
#define NWG (2*NQ*NP)    // 152 workgroups
#define KSTEPS 10        // K padded to 320
#define HROWS 160        // h2g/Ae rows (k-pairs), rows 150..159 stay zero

typedef _Float16 f16x8 __attribute__((ext_vector_type(8)));
typedef float f32x4 __attribute__((ext_vector_type(4)));
union H2U { uint32_t u; _Float16 h[2]; };

__device__ __forceinline__ uint32_t packf2(float a, float b) {
  H2U u; u.h[0] = (_Float16)a; u.h[1] = (_Float16)b; return u.u;
}
__device__ __forceinline__ float fexp(float x) {
  return __builtin_amdgcn_exp2f(x * 1.44269504088896f);
}
__device__ __forceinline__ float sigm(float x) {
  return __builtin_amdgcn_rcpf(1.0f + fexp(-x));
}
__device__ __forceinline__ float ftanh(float x) {
  return 1.0f - 2.0f * __builtin_amdgcn_rcpf(fexp(2.0f * x) + 1.0f);
}

__global__ __launch_bounds__(256) void prep_bias(
    const float* __restrict__ bihf, const float* __restrict__ bhhf,
    const float* __restrict__ bihb, const float* __restrict__ bhhb,
    float* __restrict__ bias) {
  int i = blockIdx.x * 256 + threadIdx.x;
  if (i < G4) {
    bias[i]       = bihf[i] + bhhf[i];
    bias[G4 + i]  = bihb[i] + bhhb[i];
  }
}

// ---- W_ih AND W_hh -> per-lane MFMA A-frags, gates stacked in M ----
// blk = (((kind*2+d)*NP + p)*4 + w)*KSTEPS + ks ; kind 0 = W_ih, 1 = W_hh.
// A row m=(gamma=m>>2, rr=m&3); hid = 16p + 4w + rr; k = ks*32 + (l>>4)*8 + e.
__global__ __launch_bounds__(64) void prep_wf(
    const float* __restrict__ Wihf, const float* __restrict__ Wihb,
    const float* __restrict__ Whhf, const float* __restrict__ Whhb,
    uint32_t* __restrict__ wf) {
  int blk = blockIdx.x;
  int ks = blk % KSTEPS; int tmp = blk / KSTEPS;
  int w = tmp & 3; tmp >>= 2;
  int p = tmp % NP; tmp /= NP;
  int d = tmp & 1; int kind = tmp >> 1;
  int lane = threadIdx.x;
  const float* W = kind ? (d ? Whhb : Whhf) : (d ? Wihb : Wihf);
  int m = lane & 15;
  int gamma = m >> 2, rr = m & 3;
  int hid = 16 * p + 4 * w + rr;
  int k0 = ks * 32 + (lane >> 4) * 8;
  float vals[8];
  #pragma unroll
  for (int e = 0; e < 8; ++e) {
    int k = k0 + e;
    vals[e] = (hid < 300 && k < 300) ? W[(size_t)(gamma * 300 + hid) * 300 + k] : 0.0f;
  }
  uint4 dw;
  dw.x = packf2(vals[0], vals[1]);
  dw.y = packf2(vals[2], vals[3]);
  dw.z = packf2(vals[4], vals[5]);
  dw.w = packf2(vals[6], vals[7]);
  *(uint4*)(wf + ((size_t)blk * 64 + lane) * 4) = dw;
}

// ---- zero per-wave flags + h2 double buffer (every launch: graph replay) ----
__global__ __launch_bounds__(256) void init_sync(
    uint32_t* __restrict__ flags, uint32_t* __restrict__ h2g) {
  int i = blockIdx.x * 256 + threadIdx.x;
  if (i < 8 * 128) flags[i] = 0;
  if (i < 2 * 2 * HROWS * 64) h2g[i] = 0;
}

// ---- gather embeddings -> packed f16x2, layout Ae[kk][m] (m = t*64+b) ----
// rows 150..159 zero-padded (MFMA B side must be 0, never garbage/NaN)
__global__ __launch_bounds__(256) void gather_emb(
    const int* __restrict__ x, const float* __restrict__ emb,
    uint32_t* __restrict__ Ae) {
  __shared__ __align__(16) uint32_t buf[64 * KKP];
  __shared__ int idxs[64];
  int tid = threadIdx.x;
  int m0 = blockIdx.x * 64;
  if (tid < 64) {
    int mm = m0 + tid;
    idxs[tid] = x[(size_t)(mm & 63) * TSEQ + (mm >> 6)];
  }
  __syncthreads();
  for (int i = tid; i < 64 * KKP; i += 256) {
    int mm = i / KKP, kk = i % KKP;
    float2 v = *(const float2*)(emb + (size_t)idxs[mm] * EMB + 2 * kk);
    buf[i] = packf2(v.x, v.y);
  }
  __syncthreads();
  for (int i = tid; i < 64 * KKP; i += 256) {
    int kk = i >> 6, mm = i & 63;
    Ae[(size_t)kk * MTOT + m0 + mm] = buf[mm * KKP + kk];
  }
  for (int i = tid; i < 64 * (HROWS - KKP); i += 256) {
    int kk = KKP + (i >> 6), mm = i & 63;
    Ae[(size_t)kk * MTOT + m0 + mm] = 0u;
  }
}

// ---- fused MFMA LSTM (round-11 structure; hs16 archive moved past flag) ----
// WG = (d,q,p); wave w owns hid rows [16p+4w,+4) for all 4 gates (gates in M).
// Per step: chain0 = bias + W_ih x emb_t (Ae loads issued BEFORE poll, L3
// latency hidden), chain1 = W_hh x h(s-1) (MALL relaxed loads after flag poll).
// Per-wave flags, no __syncthreads in loop. Publish: h2g store -> vmcnt(0)
// (ONE store in the drain) -> flag -> hs16 archive (off the critical path;
// read only after kernel end, so ordering vs flag is irrelevant).
__global__ __launch_bounds__(256, 1) void lstm_mfma(
    const uint32_t* __restrict__ wf, const uint32_t* __restrict__ Ae,
    const float* __restrict__ bias,
    uint32_t* __restrict__ h2g, uint32_t* __restrict__ hs16,
    uint32_t* __restrict__ flags) {
  const int wg = blockIdx.x;           // ((d*NQ+q)*NP + p)
  const int p  = wg % NP;
  const int dq = wg / NP;
  const int q  = dq & 3;
  const int d  = dq >> 2;
  const int tid = threadIdx.x;
  const int w = tid >> 6;
  const int lane = tid & 63;
  const int G = lane >> 4;             // 0..3
  const int b = lane & 15;
  const int hidbase = 16 * p + 4 * w;
  const bool valid = hidbase < 300;    // (p=18,w=3) is padding
  const int bglob = 16 * q + b;

  __shared__ float xch[4 * 256];       // per-wave 4x4 gate transpose buffer

  // A fragments in registers: W_ih (ai) + W_hh (ah), 10 x uint4 each
  uint4 ai[KSTEPS], ah[KSTEPS];
  const int blkI = (((0 * 2 + d) * NP + p) * 4 + w) * KSTEPS;
  const int blkH = (((1 * 2 + d) * NP + p) * 4 + w) * KSTEPS;
  #pragma unroll
  for (int ks = 0; ks < KSTEPS; ++ks) {
    ai[ks] = *(const uint4*)(wf + ((size_t)(blkI + ks) * 64 + lane) * 4);
    ah[ks] = *(const uint4*)(wf + ((size_t)(blkH + ks) * 64 + lane) * 4);
  }

  // per-lane bias for chain0 accumulator init (gate G, rows hidbase..+3)
  float b4[4] = {0.f, 0.f, 0.f, 0.f};
  if (valid) {
    #pragma unroll
    for (int j = 0; j < 4; ++j)
      b4[j] = bias[d * G4 + G * 300 + hidbase + j];
  }

  uint32_t* flagbase = flags + dq * 128;
  uint32_t* myflag = flagbase + p * 4 + w;
  float cstate = 0.0f;

  for (int s = 0; s < TSEQ; ++s) {
    const int t = d ? (TSEQ - 1 - s) : s;

    // issue Ae B-fragment loads FIRST: independent of h, L3 latency hides
    // under the flag poll below
    uint32_t ab[KSTEPS][4];
    {
      const uint32_t* asrc = Ae + (size_t)t * NB + bglob;
      #pragma unroll
      for (int ks = 0; ks < KSTEPS; ++ks)
        #pragma unroll
        for (int j = 0; j < 4; ++j)
          ab[ks][j] = asrc[(size_t)(ks * 16 + G * 4 + j) * MTOT];
    }

    // poll the group's 76 per-wave flags (relaxed, MALL-direct)
    if (s > 0) {
      const uint32_t sv = (uint32_t)s;
      for (;;) {
        uint32_t v0 = __hip_atomic_load(flagbase + lane, __ATOMIC_RELAXED,
                                        __HIP_MEMORY_SCOPE_AGENT);
        uint32_t v1 = sv;
        if (lane < 12)
          v1 = __hip_atomic_load(flagbase + 64 + lane, __ATOMIC_RELAXED,
                                 __HIP_MEMORY_SCOPE_AGENT);
        if (__all((int)(v0 >= sv && v1 >= sv))) break;
      }
      asm volatile("" ::: "memory");   // compile-time fence: keep h loads below
    }

    // h B-fragments straight from MALL (relaxed agent): 40 dwords
    const uint32_t* hb = h2g + (size_t)(((s + 1) & 1) * 2 + d) * (HROWS * 64)
                         + bglob;
    uint32_t bf[KSTEPS][4];
    #pragma unroll
    for (int ks = 0; ks < KSTEPS; ++ks)
      #pragma unroll
      for (int j = 0; j < 4; ++j)
        bf[ks][j] = __hip_atomic_load(hb + (size_t)(ks * 16 + G * 4 + j) * 64,
                                      __ATOMIC_RELAXED, __HIP_MEMORY_SCOPE_AGENT);

    // two independent MFMA chains: input-projection + recurrence
    f32x4 acc0, acc1;
    acc0[0] = b4[0]; acc0[1] = b4[1]; acc0[2] = b4[2]; acc0[3] = b4[3];
    acc1[0] = 0.f; acc1[1] = 0.f; acc1[2] = 0.f; acc1[3] = 0.f;
    #pragma unroll
    for (int ks = 0; ks < KSTEPS; ++ks) {
      union { uint4 u; f16x8 v; } aiu, ahu;
      union { uint32_t u[4]; f16x8 v; } abu, bfu;
      aiu.u = ai[ks]; ahu.u = ah[ks];
      abu.u[0] = ab[ks][0]; abu.u[1] = ab[ks][1];
      abu.u[2] = ab[ks][2]; abu.u[3] = ab[ks][3];
      bfu.u[0] = bf[ks][0]; bfu.u[1] = bf[ks][1];
      bfu.u[2] = bf[ks][2]; bfu.u[3] = bf[ks][3];
      acc0 = __builtin_amdgcn_mfma_f32_16x16x32_f16(aiu.v, abu.v, acc0, 0, 0, 0);
      acc1 = __builtin_amdgcn_mfma_f32_16x16x32_f16(ahu.v, bfu.v, acc1, 0, 0, 0);
    }

    // in-wave 4x4 transpose (rr x gate) via LDS, wave-synchronous
    #pragma unroll
    for (int j = 0; j < 4; ++j)
      xch[w * 256 + (j * 4 + G) * 16 + b] = acc0[j] + acc1[j];
    asm volatile("s_waitcnt lgkmcnt(0)" ::: "memory");
    __builtin_amdgcn_sched_barrier(0);
    float gi = xch[w * 256 + (G * 4 + 0) * 16 + b];
    float gf = xch[w * 256 + (G * 4 + 1) * 16 + b];
    float gg = xch[w * 256 + (G * 4 + 2) * 16 + b];
    float go = xch[w * 256 + (G * 4 + 3) * 16 + b];

    // cell update for row hidbase+G, batch bglob (c stays in register)
    float iv = sigm(gi), fv = sigm(gf), gv = ftanh(gg), ov = sigm(go);
    cstate = fv * cstate + iv * gv;
    float h = ov * ftanh(cstate);

    // pack pairs (rows even/odd) and publish
    float hp = __shfl_xor(h, 16);      // G0<->G1, G2<->G3
    uint32_t dw = packf2(h, hp);
    const int kk = (hidbase + G) >> 1; // = 8p + 2w + (G>>1), <= 149 when valid
    if (valid && (G & 1) == 0) {
      uint32_t* dst = h2g + (size_t)((s & 1) * 2 + d) * (HROWS * 64)
                      + (size_t)kk * 64 + bglob;
      __hip_atomic_store(dst, dw, __ATOMIC_RELAXED, __HIP_MEMORY_SCOPE_AGENT);
    }
    asm volatile("s_waitcnt vmcnt(0)" ::: "memory");   // drain: h2g store only
    if (lane == 0)
      __hip_atomic_store(myflag, (uint32_t)(s + 1), __ATOMIC_RELAXED,
                         __HIP_MEMORY_SCOPE_AGENT);
    // archive store AFTER the flag: off the critical path
    if (valid && (G & 1) == 0)
      hs16[((size_t)d * MTOT + (size_t)t * NB + bglob) * 152 + kk] = dw;
  }
}

// ---- logits from f16 h pairs; 16 tb per WG; softmax -> probs ----
__global__ __launch_bounds__(256) void logits_probs(
    const uint32_t* __restrict__ hs16, const float* __restrict__ Wlin,
    const float* __restrict__ blin, float* __restrict__ probs) {
  __shared__ float Ws[NT * 600];
  __shared__ float bs[NT];
  int tid = threadIdx.x;
  for (int i = tid; i < NT * 600; i += 256) Ws[i] = Wlin[i];
  if (tid < NT) bs[tid] = blin[tid];
  __syncthreads();
  int wave = tid >> 6, lane = tid & 63;
  for (int it = 0; it < 4; ++it) {
    int tb = blockIdx.x * 16 + wave * 4 + it;
    const uint32_t* hf = hs16 + (size_t)tb * 152;
    const uint32_t* hb = hs16 + ((size_t)MTOT + tb) * 152;
    uint32_t fa[3], ga[3];
    fa[0] = hf[lane]; fa[1] = hf[64 + lane];
    fa[2] = (lane < 22) ? hf[128 + lane] : 0u;
    ga[0] = hb[lane]; ga[1] = hb[64 + lane];
    ga[2] = (lane < 22) ? hb[128 + lane] : 0u;
    float p[NT];
    #pragma unroll
    for (int k = 0; k < NT; ++k) p[k] = 0.f;
    #pragma unroll
    for (int c = 0; c < 3; ++c) {
      int kk = c * 64 + lane;
      if (kk < KKP) {
        H2U uf; uf.u = fa[c];
        H2U ug; ug.u = ga[c];
        float hf0 = (float)uf.h[0], hf1 = (float)uf.h[1];
        float hb0 = (float)ug.h[0], hb1 = (float)ug.h[1];
        #pragma unroll
        for (int k = 0; k < NT; ++k)
          p[k] += hf0 * Ws[k * 600 + 2 * kk] + hf1 * Ws[k * 600 + 2 * kk + 1]
                + hb0 * Ws[k * 600 + 300 + 2 * kk] + hb1 * Ws[k * 600 + 300 + 2 * kk + 1];
      }
    }
    #pragma unroll
    for (int off = 32; off > 0; off >>= 1)
      #pragma unroll
      for (int k = 0; k < NT; ++k) p[k] += __shfl_xor(p[k], off);
    float l[NT]; float mx = -1e30f;
    #pragma unroll
    for (int k = 0; k < NT; ++k) { l[k] = p[k] + bs[k]; mx = fmaxf(mx, l[k]); }
    float ssum = 0.f;
    #pragma unroll
    for (int k = 0; k < NT; ++k) ssum += expf(l[k] - mx);
    int t = tb >> 6, bb = tb & 63;
    if (lane < NT)
      probs[((size_t)bb * TSEQ + t) * NT + lane] = expf(l[lane] - mx) / ssum;
  }
}

// ---- CRF numerator per batch ----
__global__ __launch_bounds__(256) void crf_num(
    const int* __restrict__ y, const float* __restrict__ probs,
    const float* __restrict__ strt, const float* __restrict__ endt,
    const float* __restrict__ trans, float* __restrict__ nums) {
  int b = blockIdx.x, tid = threadIdx.x;
  __shared__ float r1[256], r2[256];
  float s = 0.f, cnt = 0.f;
  for (int t = tid; t < TSEQ; t += 256) {
    int yc = y[(size_t)b * TSEQ + t];
    cnt += (yc != -1) ? 1.f : 0.f;
    if (t >= 1) {
      int yp = y[(size_t)b * TSEQ + t - 1];
      float mask = (yc != -1) ? 1.f : 0.f;
      s += mask * (trans[yp * NT + yc] + probs[((size_t)b * TSEQ + t) * NT + yc]);
    }
  }
  r1[tid] = s; r2[tid] = cnt;
  __syncthreads();
  for (int off = 128; off > 0; off >>= 1) {
    if (tid < off) { r1[tid] += r1[tid + off]; r2[tid] += r2[tid + off]; }
    __syncthreads();
  }
  if (tid == 0) {
    int y0 = y[(size_t)b * TSEQ];
    int seqlen = (int)(r2[0] + 0.5f);
    int ylast = y[(size_t)b * TSEQ + seqlen - 1];
    nums[b] = strt[y0] + probs[((size_t)b * TSEQ) * NT + y0] + r1[0] + endt[ylast];
  }
}

// ---- CRF forward algorithm: one wave per batch ----
__global__ __launch_bounds__(64) void crf_alpha(
    const int* __restrict__ y, const float* __restrict__ probs,
    const float* __restrict__ strt, const float* __restrict__ endt,
    const float* __restrict__ trans, float* __restrict__ dens) {
  int b = blockIdx.x, lane = threadIdx.x;
  __shared__ float P[TSEQ * NT];
  __shared__ float msk[TSEQ];
  for (int i = lane; i < TSEQ * NT; i += 64) P[i] = probs[(size_t)b * TSEQ * NT + i];
  for (int i = lane; i < TSEQ; i += 64) msk[i] = (y[(size_t)b * TSEQ + i] != -1) ? 1.f : 0.f;
  asm volatile("s_waitcnt lgkmcnt(0) vmcnt(0)" ::: "memory");
  int li = lane < NT ? lane : NT - 1;
  float trc[NT];
  #pragma unroll
  for (int j = 0; j < NT; ++j) trc[j] = trans[j * NT + li];
  float al = strt[li] + P[li];
  for (int t = 1; t < TSEQ; ++t) {
    float e = P[t * NT + li];
    float m = msk[t];
    float tmp[NT]; float mx = -1e30f;
    #pragma unroll
    for (int j = 0; j < NT; ++j) {
      float aj = __shfl(al, j);
      tmp[j] = aj + trc[j];
      mx = fmaxf(mx, tmp[j]);
    }
    float sum = 0.f;
    #pragma unroll
    for (int j = 0; j < NT; ++j) sum += expf(tmp[j] - mx);
    float nxt = e + mx + logf(sum);
    al = (m > 0.5f) ? nxt : al;
  }
  float vv = al + endt[li];
  float mx = -1e30f;
  #pragma unroll
  for (int j = 0; j < NT; ++j) mx = fmaxf(mx, __shfl(vv, j));
  float sum = 0.f;
  #pragma unroll
  for (int j = 0; j < NT; ++j) sum += expf(__shfl(vv, j) - mx);
  if (lane == 0) dens[b] = mx + logf(sum);
}

__global__ __launch_bounds__(64) void final_sum(
    const float* __restrict__ nums, const float* __restrict__ dens,
    float* __restrict__ out) {
  __shared__ float r[64];
  int tid = threadIdx.x;
  r[tid] = nums[tid] - dens[tid];
  __syncthreads();
  for (int off = 32; off > 0; off >>= 1) {
    if (tid < off) r[tid] += r[tid + off];
    __syncthreads();
  }
  if (tid == 0) out[(size_t)MTOT * NT] = -r[0];
}

extern "C" void kernel_launch(void* const* d_in, const int* in_sizes, int n_in,
                              void* d_out, int out_size, void* d_ws, size_t ws_size,
                              hipStream_t stream) {
  (void)in_sizes; (void)n_in; (void)out_size;
  const int*   x     = (const int*)d_in[0];
  const int*   y     = (const int*)d_in[1];
  const float* emb   = (const float*)d_in[2];
  const float* Wihf  = (const float*)d_in[3];
  const float* Whhf  = (const float*)d_in[4];
  const float* bihf  = (const float*)d_in[5];
  const float* bhhf  = (const float*)d_in[6];
  const float* Wihb  = (const float*)d_in[7];
  const float* Whhb  = (const float*)d_in[8];
  const float* bihb  = (const float*)d_in[9];
  const float* bhhb  = (const float*)d_in[10];
  const float* Wlin  = (const float*)d_in[11];
  const float* blin  = (const float*)d_in[12];
  const float* strt  = (const float*)d_in[13];
  const float* endt  = (const float*)d_in[14];
  const float* trans = (const float*)d_in[15];
  float* outp = (float*)d_out;

  char* ws = (char*)d_ws;
  const size_t OFF_WF    = 0;            // 3040 blocks * 1024 B = 3,112,960
  const size_t OFF_BIAS  = 3112960;      // 9,600
  const size_t OFF_NUMS  = 3122560;      // 256
  const size_t OFF_DENS  = 3122816;      // 256
  const size_t OFF_FLAGS = 3123072;      // 4,096
  const size_t OFF_H2G   = 3127168;      // 2*2*160*64*4 = 163,840
  const size_t OFF_AE    = 3291008;      // 160*32768*4 = 20,971,520
  const size_t OFF_HS16  = 24262528;     // 2*32768*152*4 = 39,845,888 -> 64,108,416
  if (ws_size < 64108416ull) return;

  uint32_t* wf    = (uint32_t*)(ws + OFF_WF);
  float*    bias  = (float*)(ws + OFF_BIAS);
  float*    nums  = (float*)(ws + OFF_NUMS);
  float*    dens  = (float*)(ws + OFF_DENS);
  uint32_t* flags = (uint32_t*)(ws + OFF_FLAGS);
  uint32_t* h2g   = (uint32_t*)(ws + OFF_H2G);
  uint32_t* Ae    = (uint32_t*)(ws + OFF_AE);
  uint32_t* hs16  = (uint32_t*)(ws + OFF_HS16);

  prep_wf<<<dim3(2 * 2 * NP * 4 * KSTEPS), 64, 0, stream>>>(Wihf, Wihb, Whhf, Whhb, wf);
  prep_bias<<<dim3((G4 + 255) / 256), 256, 0, stream>>>(bihf, bhhf, bihb, bhhb, bias);
  init_sync<<<dim3(160), 256, 0, stream>>>(flags, h2g);
  gather_emb<<<dim3(MTOT / 64), 256, 0, stream>>>(x, emb, Ae);
  lstm_mfma<<<dim3(NWG), 256, 0, stream>>>(wf, Ae, bias, h2g, hs16, flags);
  logits_probs<<<dim3(MTOT / 16), 256, 0, stream>>>(hs16, Wlin, blin, outp);
  crf_num<<<dim3(NB), 256, 0, stream>>>(y, outp, strt, endt, trans, nums);
  crf_alpha<<<dim3(NB), 64, 0, stream>>>(y, outp, strt, endt, trans, dens);
  final_sum<<<1, 64, 0, stream>>>(nums, dens, outp);
}